// Round 8
// baseline (604.849 us; speedup 1.0000x reference)
//
#include <hip/hip_runtime.h>

#define HIDDEN 64
#define CF 16        // features per chunk
#define NCHUNK 4     // chunks; chunk = blockIdx&3, XCD-spread
#define RANGE 8192   // nodes per histogram range (32 KB LDS per array)
#define RSHIFT 13
#define PPART 32     // edge partitions

// ---------- atomic-free degree histograms ----------
// block = (range r, partition p). LDS histograms of indeg(dst) and outdeg(src)
// for nodes in [r*RANGE, (r+1)*RANGE) over edges [p*Ep, (p+1)*Ep).
__global__ __launch_bounds__(256) void hist_kernel(const int* __restrict__ src,
                                                   const int* __restrict__ dst,
                                                   int* __restrict__ inpart,
                                                   int* __restrict__ outpart,
                                                   int E, int Ep, int Npad) {
    __shared__ int hin[RANGE];
    __shared__ int hout[RANGE];
    int r = blockIdx.x >> 5, p = blockIdx.x & 31;
    int base = r << RSHIFT;
    for (int i = threadIdx.x; i < RANGE; i += 256) { hin[i] = 0; hout[i] = 0; }
    __syncthreads();
    int es = p * Ep, ee = min(E, es + Ep);
    for (int e = es + threadIdx.x; e < ee; e += 256) {
        int d = dst[e], s = src[e];
        unsigned dd = (unsigned)(d - base), ss = (unsigned)(s - base);
        if (dd < RANGE) atomicAdd(&hin[dd], 1);
        if (ss < RANGE) atomicAdd(&hout[ss], 1);
    }
    __syncthreads();
    int* ip = inpart + (size_t)p * Npad + base;
    int* op = outpart + (size_t)p * Npad + base;
    for (int i = threadIdx.x; i < RANGE; i += 256) { ip[i] = hin[i]; op[i] = hout[i]; }
}

// ---------- per-node: indeg/outdeg totals, exclusive prefix over partitions,
// norms, padded-degree block sums ----------
__global__ __launch_bounds__(256) void prefix_kernel(int* __restrict__ inpart,
                                                     const int* __restrict__ outpart,
                                                     int* __restrict__ indeg,
                                                     float* __restrict__ nsrc,
                                                     float* __restrict__ ndst,
                                                     int* __restrict__ bsum,
                                                     int N, int Npad) {
    int t = threadIdx.x;
    int n = blockIdx.x * 256 + t;
    int run = 0, od = 0;
    if (n < N) {
#pragma unroll 4
        for (int p = 0; p < PPART; p++) {
            size_t idx = (size_t)p * Npad + n;
            int c = inpart[idx];
            inpart[idx] = run;   // exclusive prefix = partition base slot
            run += c;
            od += outpart[idx];
        }
        indeg[n] = run;
        nsrc[n] = rsqrtf(fmaxf((float)od, 1.0f));
        ndst[n] = rsqrtf(fmaxf((float)run, 1.0f));
    }
    int v = (run + 15) & ~15;   // padded degree
#pragma unroll
    for (int off = 32; off > 0; off >>= 1) v += __shfl_down(v, off, 64);
    __shared__ int s[4];
    if ((t & 63) == 0) s[t >> 6] = v;
    __syncthreads();
    if (t == 0) bsum[blockIdx.x] = s[0] + s[1] + s[2] + s[3];
}

__global__ void scan_bsum_kernel(int* __restrict__ bsum, int B) {
    __shared__ int tmp[1024];
    int t = threadIdx.x;
    tmp[t] = (t < B) ? bsum[t] : 0;
    __syncthreads();
    for (int off = 1; off < 1024; off <<= 1) {
        int u = (t >= off) ? tmp[t - off] : 0;
        __syncthreads();
        tmp[t] += u;
        __syncthreads();
    }
    if (t < B) bsum[t] = (t > 0) ? tmp[t - 1] : 0;
}

// padded inclusive scan -> row_ptr (padded CSR)
__global__ void scan_final_kernel(const int* __restrict__ indeg, const int* __restrict__ bsum,
                                  int* __restrict__ row_ptr, int N) {
    __shared__ int tmp[256];
    int t = threadIdx.x;
    int n = blockIdx.x * 256 + t;
    int v = (n < N) ? ((indeg[n] + 15) & ~15) : 0;
    tmp[t] = v;
    __syncthreads();
    for (int off = 1; off < 256; off <<= 1) {
        int u = (t >= off) ? tmp[t - off] : 0;
        __syncthreads();
        tmp[t] += u;
        __syncthreads();
    }
    if (n < N) row_ptr[n + 1] = tmp[t] + bsum[blockIdx.x];
    if (n == 0) row_ptr[0] = 0;
}

// ---------- atomic-free CSR fill: LDS cursors per (range, partition) ----------
__global__ __launch_bounds__(256) void fill_kernel(const int* __restrict__ src,
                                                   const int* __restrict__ dst,
                                                   const int* __restrict__ inpart,
                                                   const int* __restrict__ row_ptr,
                                                   int* __restrict__ col,
                                                   int E, int Ep, int Npad) {
    __shared__ int lcur[RANGE];
    int r = blockIdx.x >> 5, p = blockIdx.x & 31;
    int base = r << RSHIFT;
    for (int i = threadIdx.x; i < RANGE; i += 256) lcur[i] = 0;
    __syncthreads();
    const int* offs = inpart + (size_t)p * Npad;
    int es = p * Ep, ee = min(E, es + Ep);
    for (int e = es + threadIdx.x; e < ee; e += 256) {
        int d = dst[e];
        unsigned dd = (unsigned)(d - base);
        if (dd < RANGE) {
            int slot = row_ptr[d] + offs[d] + atomicAdd(&lcur[dd], 1);
            col[slot] = src[e];
        }
    }
}

// write sentinel N into pad slots [row_ptr[n]+indeg[n], row_ptr[n+1])
__global__ void pad_fill_kernel(const int* __restrict__ row_ptr, const int* __restrict__ indeg,
                                int* __restrict__ col, int N) {
    int n = blockIdx.x * 256 + threadIdx.x;
    if (n >= N) return;
    int j = row_ptr[n] + indeg[n];
    int e = row_ptr[n + 1];
    for (; j < e; j++) col[j] = N;
}

// zero the sentinel rows (node N) of tmp chunks + q[N]
__global__ void zsent_kernel(float* __restrict__ tmp, float* __restrict__ q, int N, int N1) {
    int l = threadIdx.x;   // 64
    int c = l >> 4, f = l & 15;
    tmp[((size_t)c * N1 + N) * CF + f] = 0.0f;
    if (l == 0) q[N] = 0.0f;
}

// ---------- embW = emb @ W0 ----------
__global__ __launch_bounds__(256) void embw_kernel(const float* __restrict__ emb,
                                                   const float* __restrict__ W,
                                                   float* __restrict__ embW, int V) {
    __shared__ float Wsh[HIDDEN * HIDDEN];
    for (int i = threadIdx.x; i < HIDDEN * HIDDEN; i += blockDim.x) Wsh[i] = W[i];
    __syncthreads();
    int lane = threadIdx.x & 63;
    int v = blockIdx.x * 4 + (threadIdx.x >> 6);
    if (v >= V) return;
    float rv = emb[(size_t)v * HIDDEN + lane];
    float o = 0.0f;
#pragma unroll
    for (int k = 0; k < HIDDEN; k++) o = fmaf(__shfl(rv, k, 64), Wsh[k * HIDDEN + lane], o);
    embW[(size_t)v * HIDDEN + lane] = o;
}

// ---------- w~ = W2 @ Wreg ; wt[64] = b2 . Wreg ----------
__global__ void wtilde_kernel(const float* __restrict__ W2, const float* __restrict__ Wreg,
                              const float* __restrict__ b2, float* __restrict__ wt) {
    int k = threadIdx.x;
    float s = 0.0f;
    for (int j = 0; j < HIDDEN; j++) s += W2[k * HIDDEN + j] * Wreg[j];
    wt[k] = s;
    float cv = b2[k] * Wreg[k];
#pragma unroll
    for (int off = 32; off > 0; off >>= 1) cv += __shfl_down(cv, off, 64);
    if (k == 0) wt[HIDDEN] = cv;
}

// ---------- gather1: tmp[c][n][f] = embW[feats[n]][c*16+f] * nsrc[n] ----------
__global__ void gather1_kernel(const int* __restrict__ feats, const float* __restrict__ embW,
                               const float* __restrict__ nsrc, float* __restrict__ hT,
                               int N, int N1, int total) {
    int idx = blockIdx.x * blockDim.x + threadIdx.x;
    if (idx >= total) return;
    int c = idx / (N * CF);
    int r = idx - c * (N * CF);
    int n = r >> 4;
    int f = r & 15;
    hT[((size_t)c * N1 + n) * CF + f] = embW[feats[n] * HIDDEN + c * CF + f] * nsrc[n];
}

// ---------- dense 64x64 layer, chunked CF16 in/out, 2-node ILP ----------
__global__ __launch_bounds__(256) void dense_kernel(const float* __restrict__ inT,
                                                    const float* __restrict__ W,
                                                    float* __restrict__ outT,
                                                    int N, int N1, int nstride) {
    __shared__ float Wsh[HIDDEN * HIDDEN];
    for (int i = threadIdx.x; i < HIDDEN * HIDDEN; i += blockDim.x) Wsh[i] = W[i];
    __syncthreads();

    int lane = threadIdx.x & 63;
    int warp = threadIdx.x >> 6;
    size_t rowoff = (size_t)(lane >> 4) * N1;
    int f = lane & 15;

    for (int n0 = blockIdx.x * 4 + warp; n0 < N; n0 += 2 * nstride) {
        int n1 = n0 + nstride;
        float rv0 = inT[(rowoff + n0) * CF + f];
        float rv1 = (n1 < N) ? inT[(rowoff + n1) * CF + f] : 0.0f;
        float o0 = 0.0f, o1 = 0.0f;
#pragma unroll
        for (int k = 0; k < HIDDEN; k++) {
            float w = Wsh[k * HIDDEN + lane];
            o0 = fmaf(__shfl(rv0, k, 64), w, o0);
            o1 = fmaf(__shfl(rv1, k, 64), w, o1);
        }
        outT[(rowoff + n0) * CF + f] = o0;
        if (n1 < N) outT[(rowoff + n1) * CF + f] = o1;
    }
}

// ---------- chunked gather-SpMM: padded CSR, float4, 2-node interleave ----------
__global__ __launch_bounds__(256) void spmm_kernel(const int* __restrict__ row_ptr,
                                                   const int* __restrict__ col,
                                                   const float* __restrict__ tmpT,
                                                   const float* __restrict__ ndst,
                                                   const float* __restrict__ nsrc,
                                                   const float* __restrict__ b,
                                                   float* __restrict__ outT,
                                                   int N, int N1, int nstride) {
    int lane = threadIdx.x & 63;
    int warp = threadIdx.x >> 6;
    int c = blockIdx.x & 3;
    int e = lane >> 2;
    int fq = lane & 3;
    const float* __restrict__ chunk = tmpT + (size_t)c * N1 * CF;
    float4 bias = ((const float4*)(b + c * CF))[fq];

    int start = (blockIdx.x >> 2) * 4 + warp;
    for (int n0 = start; n0 < N; n0 += 2 * nstride) {
        int n1 = n0 + nstride;
        int beg0 = row_ptr[n0], end0 = row_ptr[n0 + 1];
        int beg1 = 0, end1 = 0;
        if (n1 < N) { beg1 = row_ptr[n1]; end1 = row_ptr[n1 + 1]; }
        float4 acc0 = make_float4(0.f, 0.f, 0.f, 0.f);
        float4 acc1 = make_float4(0.f, 0.f, 0.f, 0.f);
        int j0 = beg0 + e, j1 = beg1 + e;
        while (j0 < end0 && j1 < end1) {
            int s0 = col[j0], s1 = col[j1];
            float4 v0 = *(const float4*)(chunk + (size_t)s0 * CF + fq * 4);
            float4 v1 = *(const float4*)(chunk + (size_t)s1 * CF + fq * 4);
            acc0.x += v0.x; acc0.y += v0.y; acc0.z += v0.z; acc0.w += v0.w;
            acc1.x += v1.x; acc1.y += v1.y; acc1.z += v1.z; acc1.w += v1.w;
            j0 += 16; j1 += 16;
        }
        while (j0 < end0) {
            int s0 = col[j0];
            float4 v0 = *(const float4*)(chunk + (size_t)s0 * CF + fq * 4);
            acc0.x += v0.x; acc0.y += v0.y; acc0.z += v0.z; acc0.w += v0.w;
            j0 += 16;
        }
        while (j1 < end1) {
            int s1 = col[j1];
            float4 v1 = *(const float4*)(chunk + (size_t)s1 * CF + fq * 4);
            acc1.x += v1.x; acc1.y += v1.y; acc1.z += v1.z; acc1.w += v1.w;
            j1 += 16;
        }
#pragma unroll
        for (int m = 4; m < 64; m <<= 1) {
            acc0.x += __shfl_xor(acc0.x, m, 64); acc0.y += __shfl_xor(acc0.y, m, 64);
            acc0.z += __shfl_xor(acc0.z, m, 64); acc0.w += __shfl_xor(acc0.w, m, 64);
            acc1.x += __shfl_xor(acc1.x, m, 64); acc1.y += __shfl_xor(acc1.y, m, 64);
            acc1.z += __shfl_xor(acc1.z, m, 64); acc1.w += __shfl_xor(acc1.w, m, 64);
        }
        if (e == 0) {
            float nd = ndst[n0], ns = nsrc[n0];
            float4 o;
            o.x = (acc0.x * nd + bias.x) * ns;
            o.y = (acc0.y * nd + bias.y) * ns;
            o.z = (acc0.z * nd + bias.z) * ns;
            o.w = (acc0.w * nd + bias.w) * ns;
            *(float4*)(outT + ((size_t)c * N1 + n0) * CF + fq * 4) = o;
            if (n1 < N) {
                nd = ndst[n1]; ns = nsrc[n1];
                o.x = (acc1.x * nd + bias.x) * ns;
                o.y = (acc1.y * nd + bias.y) * ns;
                o.z = (acc1.z * nd + bias.z) * ns;
                o.w = (acc1.w * nd + bias.w) * ns;
                *(float4*)(outT + ((size_t)c * N1 + n1) * CF + fq * 4) = o;
            }
        }
    }
}

// ---------- q[n] = hT[n] . w~ ----------
__global__ __launch_bounds__(256) void qdot_kernel(const float* __restrict__ hT,
                                                   const float* __restrict__ wt,
                                                   float* __restrict__ q, int N, int N1) {
    int lane = threadIdx.x & 63;
    int warp = threadIdx.x >> 6;
    int ns_ = lane >> 4, f = lane & 15;
    int n = (blockIdx.x * 4 + warp) * 4 + ns_;
    float acc = 0.0f;
#pragma unroll
    for (int c = 0; c < NCHUNK; c++) {
        float v = (n < N) ? hT[((size_t)c * N1 + n) * CF + f] : 0.0f;
        acc += v * wt[c * CF + f];
    }
    acc += __shfl_xor(acc, 1, 64);
    acc += __shfl_xor(acc, 2, 64);
    acc += __shfl_xor(acc, 4, 64);
    acc += __shfl_xor(acc, 8, 64);
    if (f == 0 && n < N) q[n] = acc;
}

// ---------- layer-3 scalar gather (padded CSR, 16 lanes/node) ----------
__global__ __launch_bounds__(256) void spmm3_kernel(const int* __restrict__ row_ptr,
                                                    const int* __restrict__ col,
                                                    const float* __restrict__ q,
                                                    const float* __restrict__ ndst,
                                                    float* __restrict__ nodeval, int N) {
    int lane = threadIdx.x & 63;
    int warp = threadIdx.x >> 6;
    int ns_ = lane >> 4, ln = lane & 15;
    int n = blockIdx.x * 16 + warp * 4 + ns_;
    if (n >= N) return;
    int beg = row_ptr[n], end = row_ptr[n + 1];
    float acc = 0.0f;
    for (int j = beg + ln; j < end; j += 16) acc += q[col[j]];
    acc += __shfl_xor(acc, 1, 64);
    acc += __shfl_xor(acc, 2, 64);
    acc += __shfl_xor(acc, 4, 64);
    acc += __shfl_xor(acc, 8, 64);
    if (ln == 0) nodeval[n] = acc * ndst[n];
}

// ---------- final: segmented sum over sorted gids ----------
__global__ __launch_bounds__(256) void final_kernel(const int* __restrict__ gids,
                                                    const float* __restrict__ nodeval,
                                                    const float* __restrict__ wt,
                                                    float* __restrict__ out, int N) {
    int n = blockIdx.x * 256 + threadIdx.x;
    int lane = threadIdx.x & 63;
    float c3 = wt[HIDDEN];
    float v = 0.0f;
    int g = -1;
    if (n < N) { v = nodeval[n] + c3; g = gids[n]; }
#pragma unroll
    for (int off = 1; off < 64; off <<= 1) {
        float u = __shfl_up(v, off, 64);
        int gu = __shfl_up(g, off, 64);
        if (lane >= off && gu == g) v += u;
    }
    int gn = __shfl_down(g, 1, 64);
    bool last = (lane == 63) || (gn != g);
    if (n < N && last) atomicAdd(&out[g], v);
}

extern "C" void kernel_launch(void* const* d_in, const int* in_sizes, int n_in,
                              void* d_out, int out_size, void* d_ws, size_t ws_size,
                              hipStream_t stream) {
    const int*   feats = (const int*)d_in[0];
    const int*   src   = (const int*)d_in[1];
    const int*   dst   = (const int*)d_in[2];
    const int*   gids  = (const int*)d_in[3];
    const float* emb   = (const float*)d_in[5];
    const float* Ws    = (const float*)d_in[6];
    const float* bs    = (const float*)d_in[7];
    const float* Wreg  = (const float*)d_in[8];
    float* out = (float*)d_out;

    int N = in_sizes[0];
    int E = in_sizes[1];
    int V = in_sizes[5] / HIDDEN;
    int N1 = N + 1;                 // +1 sentinel row per chunk
    int NB = (N + 255) / 256;
    int Ecap = E + 15 * N;
    int R = (N + RANGE - 1) / RANGE;        // histogram ranges
    int Npad = R * RANGE;
    int Ep = (E + PPART - 1) / PPART;       // edges per partition

    char* p = (char*)d_ws;
    int*   indeg   = (int*)p;    p += (size_t)N * 4;
    float* nsrc    = (float*)p;  p += (size_t)N * 4;
    float* ndst    = (float*)p;  p += (size_t)N * 4;
    int*   row_ptr = (int*)p;    p += (size_t)(N + 1) * 4;
    int*   bsum    = (int*)p;    p += 1024 * 4;
    float* wt      = (float*)p;  p += (HIDDEN + 1) * 4;
    float* q       = (float*)p;  p += (size_t)(N + 1) * 4;   // + sentinel
    float* nodeval = (float*)p;  p += (size_t)N * 4;
    int*   col     = (int*)p;    p += (size_t)Ecap * 4;
    p = (char*)(((uintptr_t)p + 255) & ~(uintptr_t)255);
    float* embW    = (float*)p;  p += (size_t)V * HIDDEN * 4;
    float* hbuf    = (float*)p;  p += (size_t)N1 * HIDDEN * 4;   // CF16 chunked
    float* tmp     = (float*)p;  p += (size_t)N1 * HIDDEN * 4;   // CF16 chunked

    // histogram partials alias dead-at-this-point feature buffers:
    // inpart (13.6 MB) in tmp (25.6 MB), outpart in hbuf. Both consumed before
    // zsent/gather1/spmm write tmp/hbuf (stream is in-order).
    int* inpart  = (int*)tmp;
    int* outpart = (int*)hbuf;

    hipMemsetAsync(out, 0, (size_t)out_size * 4, stream);

    // ---- atomic-free CSR build ----
    hist_kernel<<<R * PPART, 256, 0, stream>>>(src, dst, inpart, outpart, E, Ep, Npad);
    prefix_kernel<<<NB, 256, 0, stream>>>(inpart, outpart, indeg, nsrc, ndst, bsum, N, Npad);
    scan_bsum_kernel<<<1, 1024, 0, stream>>>(bsum, NB);
    scan_final_kernel<<<NB, 256, 0, stream>>>(indeg, bsum, row_ptr, N);
    fill_kernel<<<R * PPART, 256, 0, stream>>>(src, dst, inpart, row_ptr, col, E, Ep, Npad);
    pad_fill_kernel<<<NB, 256, 0, stream>>>(row_ptr, indeg, col, N);

    // ---- precomputed weights ----
    embw_kernel<<<(V + 3) / 4, 256, 0, stream>>>(emb, Ws + 0 * HIDDEN * HIDDEN, embW, V);
    wtilde_kernel<<<1, 64, 0, stream>>>(Ws + 2 * HIDDEN * HIDDEN, Wreg, bs + 2 * HIDDEN, wt);

    // ---- features ----
    zsent_kernel<<<1, 64, 0, stream>>>(tmp, q, N, N1);
    int total = N * HIDDEN;
    gather1_kernel<<<(total + 255) / 256, 256, 0, stream>>>(feats, embW, nsrc, tmp, N, N1, total);

    const int GB_SPMM = 2048;
    const int GB_DENSE = 2048;
    int sstride = GB_SPMM * 4;
    int dstride = GB_DENSE * 4;

    // layer 1: hbuf = ((A tmp)*ndst + b0)*nsrc
    spmm_kernel<<<NCHUNK * GB_SPMM, 256, 0, stream>>>(row_ptr, col, tmp, ndst, nsrc,
                                                      bs + 0 * HIDDEN, hbuf, N, N1, sstride);
    // layer 2: tmp = hbuf @ W1 ; hbuf = ((A tmp)*ndst + b1)*nsrc
    dense_kernel<<<GB_DENSE, 256, 0, stream>>>(hbuf, Ws + 1 * HIDDEN * HIDDEN, tmp, N, N1, dstride);
    spmm_kernel<<<NCHUNK * GB_SPMM, 256, 0, stream>>>(row_ptr, col, tmp, ndst, nsrc,
                                                      bs + 1 * HIDDEN, hbuf, N, N1, sstride);
    // collapsed layer 3
    qdot_kernel<<<(N + 15) / 16, 256, 0, stream>>>(hbuf, wt, q, N, N1);
    spmm3_kernel<<<(N + 15) / 16, 256, 0, stream>>>(row_ptr, col, q, ndst, nodeval, N);
    final_kernel<<<NB, 256, 0, stream>>>(gids, nodeval, wt, out, N);
}

// Round 9
// 525.340 us; speedup vs baseline: 1.1513x; 1.1513x over previous
//
#include <hip/hip_runtime.h>

#define HIDDEN 64
#define CF 16        // features per chunk
#define NCHUNK 4     // chunks; chunk = blockIdx&3, XCD-spread
#define RANGE 8192   // nodes per histogram range
#define RSHIFT 13
#define PPART 64     // edge partitions
#define PSHIFT 6

// ---------- atomic-free degree histograms (packed u16 pairs) ----------
// block = (range r, partition p). LDS histograms of indeg(dst) and outdeg(src)
// for nodes in [r*RANGE,(r+1)*RANGE) over edges [p*Ep,(p+1)*Ep).
// Counters are 2 nodes/word: node n -> word n>>1, half (n&1). Counts < 2^16.
__global__ __launch_bounds__(256) void hist_kernel(const int* __restrict__ src,
                                                   const int* __restrict__ dst,
                                                   int* __restrict__ inpart,
                                                   int* __restrict__ outpart,
                                                   int E, int Ep, int Npad2) {
    __shared__ int hin[RANGE / 2];
    __shared__ int hout[RANGE / 2];
    int r = blockIdx.x >> PSHIFT, p = blockIdx.x & (PPART - 1);
    int base = r << RSHIFT;
    for (int i = threadIdx.x; i < RANGE / 2; i += 256) { hin[i] = 0; hout[i] = 0; }
    __syncthreads();
    int es = p * Ep, ee = min(E, es + Ep);
    for (int e = es + threadIdx.x; e < ee; e += 256) {
        int d = dst[e], s = src[e];
        unsigned dd = (unsigned)(d - base), ss = (unsigned)(s - base);
        if (dd < RANGE) atomicAdd(&hin[dd >> 1], 1 << ((dd & 1) << 4));
        if (ss < RANGE) atomicAdd(&hout[ss >> 1], 1 << ((ss & 1) << 4));
    }
    __syncthreads();
    int* ip = inpart + (size_t)p * Npad2 + (base >> 1);
    int* op = outpart + (size_t)p * Npad2 + (base >> 1);
    for (int i = threadIdx.x; i < RANGE / 2; i += 256) { ip[i] = hin[i]; op[i] = hout[i]; }
}

// ---------- per-node-pair: totals, exclusive prefix over partitions, norms,
// padded-degree block sums (2 bsum entries per block of 512 nodes) ----------
__global__ __launch_bounds__(256) void prefix_kernel(int* __restrict__ inpart,
                                                     const int* __restrict__ outpart,
                                                     int* __restrict__ indeg,
                                                     float* __restrict__ nsrc,
                                                     float* __restrict__ ndst,
                                                     int* __restrict__ bsum,
                                                     int N, int Npad2) {
    int t = threadIdx.x;
    int w = blockIdx.x * 256 + t;     // word index = node pair
    int n0 = w << 1;
    int run0 = 0, run1 = 0, od0 = 0, od1 = 0;
    if (n0 < N) {
#pragma unroll 4
        for (int p = 0; p < PPART; p++) {
            size_t idx = (size_t)p * Npad2 + w;
            int c = inpart[idx];
            int o = outpart[idx];
            inpart[idx] = (run0 & 0xffff) | (run1 << 16);   // exclusive prefixes, packed
            run0 += c & 0xffff;  run1 += (c >> 16) & 0xffff;
            od0  += o & 0xffff;  od1  += (o >> 16) & 0xffff;
        }
        indeg[n0] = run0;
        nsrc[n0] = rsqrtf(fmaxf((float)od0, 1.0f));
        ndst[n0] = rsqrtf(fmaxf((float)run0, 1.0f));
        if (n0 + 1 < N) {
            indeg[n0 + 1] = run1;
            nsrc[n0 + 1] = rsqrtf(fmaxf((float)od1, 1.0f));
            ndst[n0 + 1] = rsqrtf(fmaxf((float)run1, 1.0f));
        }
    }
    int v = ((run0 + 15) & ~15) + ((run1 + 15) & ~15);   // padded degrees (0 if n>=N)
#pragma unroll
    for (int off = 32; off > 0; off >>= 1) v += __shfl_down(v, off, 64);
    __shared__ int s[4];
    if ((t & 63) == 0) s[t >> 6] = v;
    __syncthreads();
    if (t == 0) {
        bsum[2 * blockIdx.x]     = s[0] + s[1];   // nodes [512b, 512b+256)
        bsum[2 * blockIdx.x + 1] = s[2] + s[3];   // nodes [512b+256, 512b+512)
    }
}

__global__ void scan_bsum_kernel(int* __restrict__ bsum, int B) {
    __shared__ int tmp[1024];
    int t = threadIdx.x;
    tmp[t] = (t < B) ? bsum[t] : 0;
    __syncthreads();
    for (int off = 1; off < 1024; off <<= 1) {
        int u = (t >= off) ? tmp[t - off] : 0;
        __syncthreads();
        tmp[t] += u;
        __syncthreads();
    }
    if (t < B) bsum[t] = (t > 0) ? tmp[t - 1] : 0;
}

// padded inclusive scan -> row_ptr (padded CSR)
__global__ void scan_final_kernel(const int* __restrict__ indeg, const int* __restrict__ bsum,
                                  int* __restrict__ row_ptr, int N) {
    __shared__ int tmp[256];
    int t = threadIdx.x;
    int n = blockIdx.x * 256 + t;
    int v = (n < N) ? ((indeg[n] + 15) & ~15) : 0;
    tmp[t] = v;
    __syncthreads();
    for (int off = 1; off < 256; off <<= 1) {
        int u = (t >= off) ? tmp[t - off] : 0;
        __syncthreads();
        tmp[t] += u;
        __syncthreads();
    }
    if (n < N) row_ptr[n + 1] = tmp[t] + bsum[blockIdx.x];
    if (n == 0) row_ptr[0] = 0;
}

// ---------- atomic-free CSR fill: packed LDS cursors per (range,partition) ----------
__global__ __launch_bounds__(256) void fill_kernel(const int* __restrict__ src,
                                                   const int* __restrict__ dst,
                                                   const int* __restrict__ inpart,
                                                   const int* __restrict__ row_ptr,
                                                   int* __restrict__ col,
                                                   int E, int Ep, int Npad2) {
    __shared__ int lcur[RANGE / 2];
    int r = blockIdx.x >> PSHIFT, p = blockIdx.x & (PPART - 1);
    int base = r << RSHIFT;
    for (int i = threadIdx.x; i < RANGE / 2; i += 256) lcur[i] = 0;
    __syncthreads();
    const int* offs = inpart + (size_t)p * Npad2;
    int es = p * Ep, ee = min(E, es + Ep);
    for (int e = es + threadIdx.x; e < ee; e += 256) {
        int d = dst[e];
        unsigned dd = (unsigned)(d - base);
        if (dd < RANGE) {
            int sh = (dd & 1) << 4;
            int old = atomicAdd(&lcur[dd >> 1], 1 << sh);
            int lrank = (old >> sh) & 0xffff;
            int pbase = (offs[d >> 1] >> ((d & 1) << 4)) & 0xffff;
            col[row_ptr[d] + pbase + lrank] = src[e];
        }
    }
}

// write sentinel N into pad slots [row_ptr[n]+indeg[n], row_ptr[n+1])
__global__ void pad_fill_kernel(const int* __restrict__ row_ptr, const int* __restrict__ indeg,
                                int* __restrict__ col, int N) {
    int n = blockIdx.x * 256 + threadIdx.x;
    if (n >= N) return;
    int j = row_ptr[n] + indeg[n];
    int e = row_ptr[n + 1];
    for (; j < e; j++) col[j] = N;
}

// zero the sentinel rows (node N) of tmp chunks + q[N]
__global__ void zsent_kernel(float* __restrict__ tmp, float* __restrict__ q, int N, int N1) {
    int l = threadIdx.x;   // 64
    int c = l >> 4, f = l & 15;
    tmp[((size_t)c * N1 + N) * CF + f] = 0.0f;
    if (l == 0) q[N] = 0.0f;
}

// ---------- embW = emb @ W0 ----------
__global__ __launch_bounds__(256) void embw_kernel(const float* __restrict__ emb,
                                                   const float* __restrict__ W,
                                                   float* __restrict__ embW, int V) {
    __shared__ float Wsh[HIDDEN * HIDDEN];
    for (int i = threadIdx.x; i < HIDDEN * HIDDEN; i += blockDim.x) Wsh[i] = W[i];
    __syncthreads();
    int lane = threadIdx.x & 63;
    int v = blockIdx.x * 4 + (threadIdx.x >> 6);
    if (v >= V) return;
    float rv = emb[(size_t)v * HIDDEN + lane];
    float o = 0.0f;
#pragma unroll
    for (int k = 0; k < HIDDEN; k++) o = fmaf(__shfl(rv, k, 64), Wsh[k * HIDDEN + lane], o);
    embW[(size_t)v * HIDDEN + lane] = o;
}

// ---------- w~ = W2 @ Wreg ; wt[64] = b2 . Wreg ----------
__global__ void wtilde_kernel(const float* __restrict__ W2, const float* __restrict__ Wreg,
                              const float* __restrict__ b2, float* __restrict__ wt) {
    int k = threadIdx.x;
    float s = 0.0f;
    for (int j = 0; j < HIDDEN; j++) s += W2[k * HIDDEN + j] * Wreg[j];
    wt[k] = s;
    float cv = b2[k] * Wreg[k];
#pragma unroll
    for (int off = 32; off > 0; off >>= 1) cv += __shfl_down(cv, off, 64);
    if (k == 0) wt[HIDDEN] = cv;
}

// ---------- gather1: tmp[c][n][f] = embW[feats[n]][c*16+f] * nsrc[n] ----------
__global__ void gather1_kernel(const int* __restrict__ feats, const float* __restrict__ embW,
                               const float* __restrict__ nsrc, float* __restrict__ hT,
                               int N, int N1, int total) {
    int idx = blockIdx.x * blockDim.x + threadIdx.x;
    if (idx >= total) return;
    int c = idx / (N * CF);
    int r = idx - c * (N * CF);
    int n = r >> 4;
    int f = r & 15;
    hT[((size_t)c * N1 + n) * CF + f] = embW[feats[n] * HIDDEN + c * CF + f] * nsrc[n];
}

// ---------- dense 64x64 layer, chunked CF16 in/out, 2-node ILP ----------
__global__ __launch_bounds__(256) void dense_kernel(const float* __restrict__ inT,
                                                    const float* __restrict__ W,
                                                    float* __restrict__ outT,
                                                    int N, int N1, int nstride) {
    __shared__ float Wsh[HIDDEN * HIDDEN];
    for (int i = threadIdx.x; i < HIDDEN * HIDDEN; i += blockDim.x) Wsh[i] = W[i];
    __syncthreads();

    int lane = threadIdx.x & 63;
    int warp = threadIdx.x >> 6;
    size_t rowoff = (size_t)(lane >> 4) * N1;
    int f = lane & 15;

    for (int n0 = blockIdx.x * 4 + warp; n0 < N; n0 += 2 * nstride) {
        int n1 = n0 + nstride;
        float rv0 = inT[(rowoff + n0) * CF + f];
        float rv1 = (n1 < N) ? inT[(rowoff + n1) * CF + f] : 0.0f;
        float o0 = 0.0f, o1 = 0.0f;
#pragma unroll
        for (int k = 0; k < HIDDEN; k++) {
            float w = Wsh[k * HIDDEN + lane];
            o0 = fmaf(__shfl(rv0, k, 64), w, o0);
            o1 = fmaf(__shfl(rv1, k, 64), w, o1);
        }
        outT[(rowoff + n0) * CF + f] = o0;
        if (n1 < N) outT[(rowoff + n1) * CF + f] = o1;
    }
}

// ---------- chunked gather-SpMM: padded CSR, float4, 2-node interleave ----------
__global__ __launch_bounds__(256) void spmm_kernel(const int* __restrict__ row_ptr,
                                                   const int* __restrict__ col,
                                                   const float* __restrict__ tmpT,
                                                   const float* __restrict__ ndst,
                                                   const float* __restrict__ nsrc,
                                                   const float* __restrict__ b,
                                                   float* __restrict__ outT,
                                                   int N, int N1, int nstride) {
    int lane = threadIdx.x & 63;
    int warp = threadIdx.x >> 6;
    int c = blockIdx.x & 3;
    int e = lane >> 2;
    int fq = lane & 3;
    const float* __restrict__ chunk = tmpT + (size_t)c * N1 * CF;
    float4 bias = ((const float4*)(b + c * CF))[fq];

    int start = (blockIdx.x >> 2) * 4 + warp;
    for (int n0 = start; n0 < N; n0 += 2 * nstride) {
        int n1 = n0 + nstride;
        int beg0 = row_ptr[n0], end0 = row_ptr[n0 + 1];
        int beg1 = 0, end1 = 0;
        if (n1 < N) { beg1 = row_ptr[n1]; end1 = row_ptr[n1 + 1]; }
        float4 acc0 = make_float4(0.f, 0.f, 0.f, 0.f);
        float4 acc1 = make_float4(0.f, 0.f, 0.f, 0.f);
        int j0 = beg0 + e, j1 = beg1 + e;
        while (j0 < end0 && j1 < end1) {
            int s0 = col[j0], s1 = col[j1];
            float4 v0 = *(const float4*)(chunk + (size_t)s0 * CF + fq * 4);
            float4 v1 = *(const float4*)(chunk + (size_t)s1 * CF + fq * 4);
            acc0.x += v0.x; acc0.y += v0.y; acc0.z += v0.z; acc0.w += v0.w;
            acc1.x += v1.x; acc1.y += v1.y; acc1.z += v1.z; acc1.w += v1.w;
            j0 += 16; j1 += 16;
        }
        while (j0 < end0) {
            int s0 = col[j0];
            float4 v0 = *(const float4*)(chunk + (size_t)s0 * CF + fq * 4);
            acc0.x += v0.x; acc0.y += v0.y; acc0.z += v0.z; acc0.w += v0.w;
            j0 += 16;
        }
        while (j1 < end1) {
            int s1 = col[j1];
            float4 v1 = *(const float4*)(chunk + (size_t)s1 * CF + fq * 4);
            acc1.x += v1.x; acc1.y += v1.y; acc1.z += v1.z; acc1.w += v1.w;
            j1 += 16;
        }
#pragma unroll
        for (int m = 4; m < 64; m <<= 1) {
            acc0.x += __shfl_xor(acc0.x, m, 64); acc0.y += __shfl_xor(acc0.y, m, 64);
            acc0.z += __shfl_xor(acc0.z, m, 64); acc0.w += __shfl_xor(acc0.w, m, 64);
            acc1.x += __shfl_xor(acc1.x, m, 64); acc1.y += __shfl_xor(acc1.y, m, 64);
            acc1.z += __shfl_xor(acc1.z, m, 64); acc1.w += __shfl_xor(acc1.w, m, 64);
        }
        if (e == 0) {
            float nd = ndst[n0], ns = nsrc[n0];
            float4 o;
            o.x = (acc0.x * nd + bias.x) * ns;
            o.y = (acc0.y * nd + bias.y) * ns;
            o.z = (acc0.z * nd + bias.z) * ns;
            o.w = (acc0.w * nd + bias.w) * ns;
            *(float4*)(outT + ((size_t)c * N1 + n0) * CF + fq * 4) = o;
            if (n1 < N) {
                nd = ndst[n1]; ns = nsrc[n1];
                o.x = (acc1.x * nd + bias.x) * ns;
                o.y = (acc1.y * nd + bias.y) * ns;
                o.z = (acc1.z * nd + bias.z) * ns;
                o.w = (acc1.w * nd + bias.w) * ns;
                *(float4*)(outT + ((size_t)c * N1 + n1) * CF + fq * 4) = o;
            }
        }
    }
}

// ---------- q[n] = hT[n] . w~ ----------
__global__ __launch_bounds__(256) void qdot_kernel(const float* __restrict__ hT,
                                                   const float* __restrict__ wt,
                                                   float* __restrict__ q, int N, int N1) {
    int lane = threadIdx.x & 63;
    int warp = threadIdx.x >> 6;
    int ns_ = lane >> 4, f = lane & 15;
    int n = (blockIdx.x * 4 + warp) * 4 + ns_;
    float acc = 0.0f;
#pragma unroll
    for (int c = 0; c < NCHUNK; c++) {
        float v = (n < N) ? hT[((size_t)c * N1 + n) * CF + f] : 0.0f;
        acc += v * wt[c * CF + f];
    }
    acc += __shfl_xor(acc, 1, 64);
    acc += __shfl_xor(acc, 2, 64);
    acc += __shfl_xor(acc, 4, 64);
    acc += __shfl_xor(acc, 8, 64);
    if (f == 0 && n < N) q[n] = acc;
}

// ---------- layer-3 scalar gather (padded CSR, 16 lanes/node) ----------
__global__ __launch_bounds__(256) void spmm3_kernel(const int* __restrict__ row_ptr,
                                                    const int* __restrict__ col,
                                                    const float* __restrict__ q,
                                                    const float* __restrict__ ndst,
                                                    float* __restrict__ nodeval, int N) {
    int lane = threadIdx.x & 63;
    int warp = threadIdx.x >> 6;
    int ns_ = lane >> 4, ln = lane & 15;
    int n = blockIdx.x * 16 + warp * 4 + ns_;
    if (n >= N) return;
    int beg = row_ptr[n], end = row_ptr[n + 1];
    float acc = 0.0f;
    for (int j = beg + ln; j < end; j += 16) acc += q[col[j]];
    acc += __shfl_xor(acc, 1, 64);
    acc += __shfl_xor(acc, 2, 64);
    acc += __shfl_xor(acc, 4, 64);
    acc += __shfl_xor(acc, 8, 64);
    if (ln == 0) nodeval[n] = acc * ndst[n];
}

// ---------- final: segmented sum over sorted gids ----------
__global__ __launch_bounds__(256) void final_kernel(const int* __restrict__ gids,
                                                    const float* __restrict__ nodeval,
                                                    const float* __restrict__ wt,
                                                    float* __restrict__ out, int N) {
    int n = blockIdx.x * 256 + threadIdx.x;
    int lane = threadIdx.x & 63;
    float c3 = wt[HIDDEN];
    float v = 0.0f;
    int g = -1;
    if (n < N) { v = nodeval[n] + c3; g = gids[n]; }
#pragma unroll
    for (int off = 1; off < 64; off <<= 1) {
        float u = __shfl_up(v, off, 64);
        int gu = __shfl_up(g, off, 64);
        if (lane >= off && gu == g) v += u;
    }
    int gn = __shfl_down(g, 1, 64);
    bool last = (lane == 63) || (gn != g);
    if (n < N && last) atomicAdd(&out[g], v);
}

extern "C" void kernel_launch(void* const* d_in, const int* in_sizes, int n_in,
                              void* d_out, int out_size, void* d_ws, size_t ws_size,
                              hipStream_t stream) {
    const int*   feats = (const int*)d_in[0];
    const int*   src   = (const int*)d_in[1];
    const int*   dst   = (const int*)d_in[2];
    const int*   gids  = (const int*)d_in[3];
    const float* emb   = (const float*)d_in[5];
    const float* Ws    = (const float*)d_in[6];
    const float* bs    = (const float*)d_in[7];
    const float* Wreg  = (const float*)d_in[8];
    float* out = (float*)d_out;

    int N = in_sizes[0];
    int E = in_sizes[1];
    int V = in_sizes[5] / HIDDEN;
    int N1 = N + 1;                 // +1 sentinel row per chunk
    int NB = (N + 255) / 256;
    int NB2 = (N + 511) / 512;      // prefix blocks (512 nodes each)
    int Ecap = E + 15 * N;
    int R = (N + RANGE - 1) / RANGE;        // histogram ranges
    int Npad2 = R * (RANGE / 2);            // packed words per partition
    int Ep = (E + PPART - 1) / PPART;       // edges per partition

    char* p = (char*)d_ws;
    int*   indeg   = (int*)p;    p += (size_t)N * 4;
    float* nsrc    = (float*)p;  p += (size_t)N * 4;
    float* ndst    = (float*)p;  p += (size_t)N * 4;
    int*   row_ptr = (int*)p;    p += (size_t)(N + 1) * 4;
    int*   bsum    = (int*)p;    p += 1024 * 4;
    float* wt      = (float*)p;  p += (HIDDEN + 1) * 4;
    float* q       = (float*)p;  p += (size_t)(N + 1) * 4;   // + sentinel
    float* nodeval = (float*)p;  p += (size_t)N * 4;
    int*   col     = (int*)p;    p += (size_t)Ecap * 4;
    p = (char*)(((uintptr_t)p + 255) & ~(uintptr_t)255);
    float* embW    = (float*)p;  p += (size_t)V * HIDDEN * 4;
    float* hbuf    = (float*)p;  p += (size_t)N1 * HIDDEN * 4;   // CF16 chunked
    float* tmp     = (float*)p;  p += (size_t)N1 * HIDDEN * 4;   // CF16 chunked

    // packed histogram partials (PPART * Npad2 ints = 13.6 MB each) alias
    // dead-at-this-point feature buffers; consumed before tmp/hbuf are written.
    int* inpart  = (int*)tmp;
    int* outpart = (int*)hbuf;

    hipMemsetAsync(out, 0, (size_t)out_size * 4, stream);

    // ---- atomic-free CSR build ----
    hist_kernel<<<R * PPART, 256, 0, stream>>>(src, dst, inpart, outpart, E, Ep, Npad2);
    prefix_kernel<<<NB2, 256, 0, stream>>>(inpart, outpart, indeg, nsrc, ndst, bsum, N, Npad2);
    scan_bsum_kernel<<<1, 1024, 0, stream>>>(bsum, 2 * NB2);
    scan_final_kernel<<<NB, 256, 0, stream>>>(indeg, bsum, row_ptr, N);
    fill_kernel<<<R * PPART, 256, 0, stream>>>(src, dst, inpart, row_ptr, col, E, Ep, Npad2);
    pad_fill_kernel<<<NB, 256, 0, stream>>>(row_ptr, indeg, col, N);

    // ---- precomputed weights ----
    embw_kernel<<<(V + 3) / 4, 256, 0, stream>>>(emb, Ws + 0 * HIDDEN * HIDDEN, embW, V);
    wtilde_kernel<<<1, 64, 0, stream>>>(Ws + 2 * HIDDEN * HIDDEN, Wreg, bs + 2 * HIDDEN, wt);

    // ---- features ----
    zsent_kernel<<<1, 64, 0, stream>>>(tmp, q, N, N1);
    int total = N * HIDDEN;
    gather1_kernel<<<(total + 255) / 256, 256, 0, stream>>>(feats, embW, nsrc, tmp, N, N1, total);

    const int GB_SPMM = 2048;
    const int GB_DENSE = 2048;
    int sstride = GB_SPMM * 4;
    int dstride = GB_DENSE * 4;

    // layer 1: hbuf = ((A tmp)*ndst + b0)*nsrc
    spmm_kernel<<<NCHUNK * GB_SPMM, 256, 0, stream>>>(row_ptr, col, tmp, ndst, nsrc,
                                                      bs + 0 * HIDDEN, hbuf, N, N1, sstride);
    // layer 2: tmp = hbuf @ W1 ; hbuf = ((A tmp)*ndst + b1)*nsrc
    dense_kernel<<<GB_DENSE, 256, 0, stream>>>(hbuf, Ws + 1 * HIDDEN * HIDDEN, tmp, N, N1, dstride);
    spmm_kernel<<<NCHUNK * GB_SPMM, 256, 0, stream>>>(row_ptr, col, tmp, ndst, nsrc,
                                                      bs + 1 * HIDDEN, hbuf, N, N1, sstride);
    // collapsed layer 3
    qdot_kernel<<<(N + 15) / 16, 256, 0, stream>>>(hbuf, wt, q, N, N1);
    spmm3_kernel<<<(N + 15) / 16, 256, 0, stream>>>(row_ptr, col, q, ndst, nodeval, N);
    final_kernel<<<NB, 256, 0, stream>>>(gids, nodeval, wt, out, N);
}